// Round 23
// baseline (356.119 us; speedup 1.0000x reference)
//
#include <hip/hip_runtime.h>
#include <math.h>

#define T_TOK 4096
#define DM 1024
#define HID 4096
#define NEXP 8
#define MAXT 39   // max total 128-row tiles: 4096/128 + 7
#define NG1  1248 // GEMM1 matmul blocks; cvt-w2 tail = [NG1, NG1+512); aux = NG1+512

typedef unsigned short u16;
typedef __attribute__((ext_vector_type(8))) short short8;
typedef __attribute__((ext_vector_type(4))) float f32x4;

__device__ __forceinline__ u16 f2bf(float f){
  unsigned u = __float_as_uint(f);
  u += 0x7FFF + ((u >> 16) & 1);
  return (u16)(u >> 16);
}

// ---- workspace layout (byte offsets) ----
#define GATE_OFF   0u          // float[4096]
#define CNT_OFF    16384u      // int[8]
#define LIST_OFF   16512u      // int[8][4096]
#define PROBS_OFF  147584u     // float[4096][8]
#define XB_OFF     278656u     // bf16[4096][1024]
#define H_OFF      8667264u    // bf16[4096][4096]
#define W2B_OFF    109330560u  // bf16[8][1024][4096] = 67MB

__device__ __forceinline__ void glds16(const void* g, void* l){
  __builtin_amdgcn_global_load_lds((const __attribute__((address_space(1))) void*)g,
                                   (__attribute__((address_space(3))) void*)l, 16, 0, 0);
}

__global__ void zero_cnt_kernel(int* cnt){
  if (threadIdx.x < NEXP) cnt[threadIdx.x] = 0;
}

// one wave per token: gating + routing + x->bf16 conversion (R19-exact)
__global__ __launch_bounds__(256) void gate_kernel(
    const float* __restrict__ x, const float* __restrict__ gw,
    float* __restrict__ gateo, int* __restrict__ cnt, int* __restrict__ list,
    float* __restrict__ probs, u16* __restrict__ xb)
{
  int tid = threadIdx.x;
  int lane = tid & 63;
  int w = tid >> 6;
  int t = blockIdx.x * 4 + w;

  const float4* x4 = (const float4*)(x + (size_t)t * DM);
  const float4* g4 = (const float4*)gw;

  float acc[8] = {0,0,0,0,0,0,0,0};
  #pragma unroll
  for (int i = 0; i < 4; i++){
    int p = i * 64 + lane;
    float4 xv = x4[p];
    ushort4 pk;
    pk.x = f2bf(xv.x); pk.y = f2bf(xv.y); pk.z = f2bf(xv.z); pk.w = f2bf(xv.w);
    *(ushort4*)&xb[(size_t)t * DM + (size_t)p * 4] = pk;
    #pragma unroll
    for (int e = 0; e < NEXP; e++){
      float4 gv = g4[e * 256 + p];
      acc[e] += xv.x * gv.x + xv.y * gv.y + xv.z * gv.z + xv.w * gv.w;
    }
  }
  #pragma unroll
  for (int e = 0; e < NEXP; e++){
    #pragma unroll
    for (int off = 32; off; off >>= 1)
      acc[e] += __shfl_xor(acc[e], off);
  }
  if (lane == 0){
    float mx = acc[0];
    #pragma unroll
    for (int e = 1; e < NEXP; e++) mx = fmaxf(mx, acc[e]);
    float p[8]; float s = 0.f;
    #pragma unroll
    for (int e = 0; e < NEXP; e++){ p[e] = expf(acc[e] - mx); s += p[e]; }
    float inv = 1.f / s;
    int be = 0; float bp = p[0];
    #pragma unroll
    for (int e = 1; e < NEXP; e++){ if (p[e] > bp){ bp = p[e]; be = e; } }
    #pragma unroll
    for (int e = 0; e < NEXP; e++) probs[(size_t)t * 8 + e] = p[e] * inv;
    gateo[t] = bp * inv;
    int pos = atomicAdd(&cnt[be], 1);
    list[be * T_TOK + pos] = t;
  }
}

// GEMM1 (R19-exact: 128x128, BK=64, 4 waves 2x2, single 32KB LDS, glds-A bf16
// + reg-staged fp32 w1, 2 barriers/K-step, lb(256,3)) FUSED with:
//   - cvt-w2 tail blocks [NG1, NG1+512): fp32->bf16, hides in GEMM1's shadow
//   - aux-loss tail block (bid == NG1+512): deterministic reduction over probs
//     (depends only on gate's outputs; saves a 5us serial 1-block dispatch)
__global__ __launch_bounds__(256, 3) void ffn_gemm1(
    const u16*  __restrict__ Aall,   // xb bf16 [4096][1024]
    const float* __restrict__ Bf,    // w1 fp32 [E][4096][1024]
    const float* __restrict__ bias,  // b1
    const int*  __restrict__ cnt,
    const int*  __restrict__ list,
    u16*  __restrict__ hOut,
    const float* __restrict__ w2,    // cvt src
    u16*  __restrict__ w2b,          // cvt dst
    const float* __restrict__ probs, // aux input
    float* __restrict__ aux_out)     // aux output
{
  int bid = blockIdx.x;
  int tid = threadIdx.x;

  __shared__ u16 As[8192];           // [128][64] swizzled, 16KB (aux aliases it)
  __shared__ u16 Bs[8192];

  if (bid == NG1 + 512){
    // ---- aux-loss tail block (deterministic tree reduction)
    float* sm = (float*)As;          // 2048 floats = 8KB <= 16KB
    float s[8] = {0,0,0,0,0,0,0,0};
    for (int i = 0; i < 16; i++){
      int t = i * 256 + tid;
      #pragma unroll
      for (int e = 0; e < 8; e++) s[e] += probs[(size_t)t * 8 + e];
    }
    #pragma unroll
    for (int e = 0; e < 8; e++) sm[tid * 8 + e] = s[e];
    __syncthreads();
    for (int st = 128; st; st >>= 1){
      if (tid < st){
        #pragma unroll
        for (int e = 0; e < 8; e++) sm[tid * 8 + e] += sm[(tid + st) * 8 + e];
      }
      __syncthreads();
    }
    if (tid == 0){
      float a = 0.f;
      #pragma unroll
      for (int e = 0; e < 8; e++){
        float f = (float)cnt[e] / (float)T_TOK;
        float P = sm[e] / (float)T_TOK;
        a += f * P;
      }
      aux_out[0] = 0.01f * (float)NEXP * a;
    }
    return;
  }

  if (bid >= NG1){
    // ---- cvt-w2 tail: grid-stride fp32->bf16, 32B read / 16B write per iter
    const size_t TOT = (size_t)NEXP * DM * HID / 8;
    size_t stride = (size_t)512 * 256;
    for (size_t g = (size_t)(bid - NG1) * 256 + tid; g < TOT; g += stride){
      const float4* s = (const float4*)w2 + g * 2;
      float4 a = s[0], c = s[1];
      uint4 p;
      p.x = (unsigned)f2bf(a.x) | ((unsigned)f2bf(a.y) << 16);
      p.y = (unsigned)f2bf(a.z) | ((unsigned)f2bf(a.w) << 16);
      p.z = (unsigned)f2bf(c.x) | ((unsigned)f2bf(c.y) << 16);
      p.w = (unsigned)f2bf(c.z) | ((unsigned)f2bf(c.w) << 16);
      ((uint4*)w2b)[g] = p;
    }
    return;
  }

  constexpr int NT = 32, KS = 16;
  int nt = bid % NT;
  int t  = bid / NT;

  int e = -1, mt = 0, accT = 0;
  #pragma unroll
  for (int i = 0; i < NEXP; i++){
    int nti = (cnt[i] + 127) >> 7;
    if (e < 0 && t < accT + nti){ e = i; mt = t - accT; }
    accT += nti;
  }
  if (e < 0) return;
  int ne = cnt[e];
  int m0 = mt * 128;
  const int* lst = list + e * T_TOK;
  int n0 = nt * 128;

  int lane = tid & 63;
  int w    = tid >> 6;               // 4 waves
  int wm = w >> 1, wn = w & 1;       // 2M x 2N; wave out 64x64
  int fr = lane & 15, fq = lane >> 4;

  // A staging via glds (both-sides swizzle)
  const u16* aS[4]; int aDst[4];
  #pragma unroll
  for (int i = 0; i < 4; i++){
    int seg = w * 4 + i;
    int rr  = seg * 8 + (lane >> 3);
    int gg  = (lane & 7) ^ (rr & 7);
    int mrow = m0 + rr; if (mrow > ne - 1) mrow = ne - 1;
    aS[i] = Aall + (size_t)lst[mrow] * DM + gg * 8;
    aDst[i] = seg * 512;
  }

  // B reg-staging: 1024 chunks; thread owns 4
  const float* bS[4]; int bDst[4];
  #pragma unroll
  for (int i = 0; i < 4; i++){
    int cc = i * 256 + tid;
    int rr = cc >> 3, sl = cc & 7;
    int gg = sl ^ (rr & 7);
    bS[i] = Bf + ((size_t)e * HID + n0 + rr) * DM + gg * 8;
    bDst[i] = rr * 64 + sl * 8;
  }

  f32x4 acc[4][4];
  #pragma unroll
  for (int m = 0; m < 4; m++)
    #pragma unroll
    for (int n = 0; n < 4; n++)
      acc[m][n] = (f32x4){0.f, 0.f, 0.f, 0.f};

  float4 br0[4], br1[4];
  #pragma unroll
  for (int i = 0; i < 4; i++){
    const float4* s = (const float4*)bS[i];
    br0[i] = s[0]; br1[i] = s[1];
  }

  for (int ks = 0; ks < KS; ++ks){
    if (ks) __syncthreads();
    size_t ko = (size_t)ks * 64;
    #pragma unroll
    for (int i = 0; i < 4; i++) glds16(aS[i] + ko, &As[aDst[i]]);
    #pragma unroll
    for (int i = 0; i < 4; i++){
      uint4 pk;
      pk.x = (unsigned)f2bf(br0[i].x) | ((unsigned)f2bf(br0[i].y) << 16);
      pk.y = (unsigned)f2bf(br0[i].z) | ((unsigned)f2bf(br0[i].w) << 16);
      pk.z = (unsigned)f2bf(br1[i].x) | ((unsigned)f2bf(br1[i].y) << 16);
      pk.w = (unsigned)f2bf(br1[i].z) | ((unsigned)f2bf(br1[i].w) << 16);
      *(uint4*)&Bs[bDst[i]] = pk;
    }
    if (ks + 1 < KS){
      #pragma unroll
      for (int i = 0; i < 4; i++){
        const float4* s = (const float4*)(bS[i] + (ks + 1) * 64);
        br0[i] = s[0]; br1[i] = s[1];
      }
    }
    __syncthreads();
    #pragma unroll
    for (int kc = 0; kc < 2; kc++){
      short8 afr[4], bfr[4];
      #pragma unroll
      for (int m = 0; m < 4; m++){
        int row  = wm * 64 + m * 16 + fr;
        int slot = (kc * 4 + fq) ^ (row & 7);
        afr[m] = *(const short8*)&As[row * 64 + slot * 8];
      }
      #pragma unroll
      for (int n = 0; n < 4; n++){
        int row  = wn * 64 + n * 16 + fr;
        int slot = (kc * 4 + fq) ^ (row & 7);
        bfr[n] = *(const short8*)&Bs[row * 64 + slot * 8];
      }
      #pragma unroll
      for (int m = 0; m < 4; m++)
        #pragma unroll
        for (int n = 0; n < 4; n++)
          acc[m][n] = __builtin_amdgcn_mfma_f32_16x16x32_bf16(afr[m], bfr[n], acc[m][n], 0, 0, 0);
    }
  }

  #pragma unroll
  for (int n = 0; n < 4; n++){
    int col = n0 + wn * 64 + n * 16 + fr;
    float bv = bias[(size_t)e * HID + col];
    #pragma unroll
    for (int m = 0; m < 4; m++){
      int rbase = m0 + wm * 64 + m * 16 + fq * 4;
      f32x4 v = acc[m][n];
      #pragma unroll
      for (int i = 0; i < 4; i++){
        int mrow = rbase + i;
        if (mrow < ne){
          int tok = lst[mrow];
          float val = v[i] + bv;
          float gl = 0.5f * val * (1.0f + erff(val * 0.70710678118654752f));
          hOut[(size_t)tok * HID + col] = f2bf(gl);
        }
      }
    }
  }
}

// GEMM2, R16/R19-exact bf16 staging (128x128, BK=64, 4 waves, single 32KB LDS,
// glds-direct bf16 both operands, lb(256,3)), split-K=4 with ATOMIC epilogue:
// each sk atomically adds gate*(val + b2*[sk==0]) into the pre-zeroed out
// buffer — removes the 64MB PART write + 80MB reduce pass + reduce dispatch.
__global__ __launch_bounds__(256, 3) void ffn_gemm2(
    const u16*  __restrict__ Aall,   // h bf16 [4096][4096]
    const u16*  __restrict__ Bb,     // w2b bf16 [E][1024][4096]
    const float* __restrict__ bias,  // b2
    const int*  __restrict__ cnt,
    const int*  __restrict__ list,
    const float* __restrict__ gate,  // gate scores [4096]
    float* __restrict__ out)         // pre-zeroed fp32 [4096][1024]
{
  constexpr int NT = 8, KS = 16;
  int bid = blockIdx.x;
  int nt = bid % NT;
  int r1 = bid / NT;
  int t  = r1 % MAXT;
  int sk = r1 / MAXT;

  int e = -1, mt = 0, accT = 0;
  #pragma unroll
  for (int i = 0; i < NEXP; i++){
    int nti = (cnt[i] + 127) >> 7;
    if (e < 0 && t < accT + nti){ e = i; mt = t - accT; }
    accT += nti;
  }
  if (e < 0) return;
  int ne = cnt[e];
  int m0 = mt * 128;
  const int* lst = list + e * T_TOK;
  int n0 = nt * 128;
  int koff = sk * (KS * 64);

  __shared__ u16 As[8192];
  __shared__ u16 Bs[8192];

  int tid  = threadIdx.x;
  int lane = tid & 63;
  int w    = tid >> 6;
  int wm = w >> 1, wn = w & 1;
  int fr = lane & 15, fq = lane >> 4;

  const u16* aS[4]; const u16* bS[4]; int dst[4];
  #pragma unroll
  for (int i = 0; i < 4; i++){
    int seg = w * 4 + i;
    int r   = seg * 8 + (lane >> 3);
    int g   = (lane & 7) ^ (r & 7);
    int mrow = m0 + r; if (mrow > ne - 1) mrow = ne - 1;
    aS[i] = Aall + (size_t)lst[mrow] * HID + koff + g * 8;
    bS[i] = Bb + (size_t)e * DM * HID + (size_t)(n0 + r) * HID + koff + g * 8;
    dst[i] = seg * 512;
  }

  f32x4 acc[4][4];
  #pragma unroll
  for (int m = 0; m < 4; m++)
    #pragma unroll
    for (int n = 0; n < 4; n++)
      acc[m][n] = (f32x4){0.f, 0.f, 0.f, 0.f};

  for (int ks = 0; ks < KS; ++ks){
    if (ks) __syncthreads();
    size_t ko = (size_t)ks * 64;
    #pragma unroll
    for (int i = 0; i < 4; i++) glds16(aS[i] + ko, &As[dst[i]]);
    #pragma unroll
    for (int i = 0; i < 4; i++) glds16(bS[i] + ko, &Bs[dst[i]]);
    __syncthreads();
    #pragma unroll
    for (int kc = 0; kc < 2; kc++){
      short8 afr[4], bfr[4];
      #pragma unroll
      for (int m = 0; m < 4; m++){
        int row  = wm * 64 + m * 16 + fr;
        int slot = (kc * 4 + fq) ^ (row & 7);
        afr[m] = *(const short8*)&As[row * 64 + slot * 8];
      }
      #pragma unroll
      for (int n = 0; n < 4; n++){
        int row  = wn * 64 + n * 16 + fr;
        int slot = (kc * 4 + fq) ^ (row & 7);
        bfr[n] = *(const short8*)&Bs[row * 64 + slot * 8];
      }
      #pragma unroll
      for (int m = 0; m < 4; m++)
        #pragma unroll
        for (int n = 0; n < 4; n++)
          acc[m][n] = __builtin_amdgcn_mfma_f32_16x16x32_bf16(afr[m], bfr[n], acc[m][n], 0, 0, 0);
    }
  }

  #pragma unroll
  for (int n = 0; n < 4; n++){
    int col = n0 + wn * 64 + n * 16 + fr;
    float bv = (sk == 0) ? bias[(size_t)e * DM + col] : 0.f;
    #pragma unroll
    for (int m = 0; m < 4; m++){
      int rbase = m0 + wm * 64 + m * 16 + fq * 4;
      f32x4 v = acc[m][n];
      #pragma unroll
      for (int i = 0; i < 4; i++){
        int mrow = rbase + i;
        if (mrow < ne){
          int tok = lst[mrow];
          atomicAdd(&out[(size_t)tok * DM + col], gate[tok] * (v[i] + bv));
        }
      }
    }
  }
}

extern "C" void kernel_launch(void* const* d_in, const int* in_sizes, int n_in,
                              void* d_out, int out_size, void* d_ws, size_t ws_size,
                              hipStream_t stream) {
  const float* x   = (const float*)d_in[0];
  const float* gw  = (const float*)d_in[1];
  const float* w1  = (const float*)d_in[2];
  const float* b1  = (const float*)d_in[3];
  const float* w2  = (const float*)d_in[4];
  const float* b2  = (const float*)d_in[5];

  char* ws = (char*)d_ws;
  float* gateo = (float*)(ws + GATE_OFF);
  int*   cnt   = (int*)  (ws + CNT_OFF);
  int*   list  = (int*)  (ws + LIST_OFF);
  float* probs = (float*)(ws + PROBS_OFF);
  u16*   xb    = (u16*)  (ws + XB_OFF);
  u16*   h     = (u16*)  (ws + H_OFF);
  u16*   w2b   = (u16*)  (ws + W2B_OFF);

  float* out = (float*)d_out;
  float* aux = out + (size_t)T_TOK * DM;

  // zero the output (atomic-accumulation target); stream-ordered, capture-safe
  hipMemsetAsync(d_out, 0, (size_t)out_size * sizeof(float), stream);
  hipLaunchKernelGGL(zero_cnt_kernel, dim3(1), dim3(64), 0, stream, cnt);
  hipLaunchKernelGGL(gate_kernel, dim3(T_TOK / 4), dim3(256), 0, stream,
                     x, gw, gateo, cnt, list, probs, xb);

  // GEMM1 (fp32-direct w1) + cvt-w2 tail + aux tail block
  hipLaunchKernelGGL(ffn_gemm1, dim3(NG1 + 512 + 1), dim3(256), 0, stream,
                     xb, w1, b1, cnt, list, h, w2, w2b, probs, aux);
  // GEMM2 (bf16 w2b), split-K=4, atomic epilogue into out
  hipLaunchKernelGGL(ffn_gemm2, dim3(4 * MAXT * 8), dim3(256), 0, stream,
                     h, w2b, b2, cnt, list, gateo, out);
}

// Round 24
// 296.196 us; speedup vs baseline: 1.2023x; 1.2023x over previous
//
#include <hip/hip_runtime.h>
#include <math.h>

#define T_TOK 4096
#define DM 1024
#define HID 4096
#define NEXP 8
#define MAXT 39   // max total 128-row tiles: 4096/128 + 7
#define NG1  1248 // GEMM1 matmul blocks; cvt tail = bids [NG1, NG1+512)

typedef unsigned short u16;
typedef __attribute__((ext_vector_type(8))) short short8;
typedef __attribute__((ext_vector_type(4))) float f32x4;

__device__ __forceinline__ u16 f2bf(float f){
  unsigned u = __float_as_uint(f);
  u += 0x7FFF + ((u >> 16) & 1);
  return (u16)(u >> 16);
}

// ---- workspace layout (byte offsets) ----
#define GATE_OFF   0u          // float[4096]
#define CNT_OFF    16384u      // int[8]
#define LIST_OFF   16512u      // int[8][4096]
#define PROBS_OFF  147584u     // float[4096][8]
#define XB_OFF     278656u     // bf16[4096][1024]
#define H_OFF      8667264u    // bf16[4096][4096]
#define PART_OFF   42221696u   // float[4][4096][1024] = 64MB
#define W2B_OFF    109330560u  // bf16[8][1024][4096] = 67MB

__device__ __forceinline__ void glds16(const void* g, void* l){
  __builtin_amdgcn_global_load_lds((const __attribute__((address_space(1))) void*)g,
                                   (__attribute__((address_space(3))) void*)l, 16, 0, 0);
}

__global__ void zero_cnt_kernel(int* cnt){
  if (threadIdx.x < NEXP) cnt[threadIdx.x] = 0;
}

// one wave per token: gating + routing + x->bf16 conversion
__global__ __launch_bounds__(256) void gate_kernel(
    const float* __restrict__ x, const float* __restrict__ gw,
    float* __restrict__ gateo, int* __restrict__ cnt, int* __restrict__ list,
    float* __restrict__ probs, u16* __restrict__ xb)
{
  int tid = threadIdx.x;
  int lane = tid & 63;
  int w = tid >> 6;
  int t = blockIdx.x * 4 + w;

  const float4* x4 = (const float4*)(x + (size_t)t * DM);
  const float4* g4 = (const float4*)gw;

  float acc[8] = {0,0,0,0,0,0,0,0};
  #pragma unroll
  for (int i = 0; i < 4; i++){
    int p = i * 64 + lane;
    float4 xv = x4[p];
    ushort4 pk;
    pk.x = f2bf(xv.x); pk.y = f2bf(xv.y); pk.z = f2bf(xv.z); pk.w = f2bf(xv.w);
    *(ushort4*)&xb[(size_t)t * DM + (size_t)p * 4] = pk;
    #pragma unroll
    for (int e = 0; e < NEXP; e++){
      float4 gv = g4[e * 256 + p];
      acc[e] += xv.x * gv.x + xv.y * gv.y + xv.z * gv.z + xv.w * gv.w;
    }
  }
  #pragma unroll
  for (int e = 0; e < NEXP; e++){
    #pragma unroll
    for (int off = 32; off; off >>= 1)
      acc[e] += __shfl_xor(acc[e], off);
  }
  if (lane == 0){
    float mx = acc[0];
    #pragma unroll
    for (int e = 1; e < NEXP; e++) mx = fmaxf(mx, acc[e]);
    float p[8]; float s = 0.f;
    #pragma unroll
    for (int e = 0; e < NEXP; e++){ p[e] = expf(acc[e] - mx); s += p[e]; }
    float inv = 1.f / s;
    int be = 0; float bp = p[0];
    #pragma unroll
    for (int e = 1; e < NEXP; e++){ if (p[e] > bp){ bp = p[e]; be = e; } }
    #pragma unroll
    for (int e = 0; e < NEXP; e++) probs[(size_t)t * 8 + e] = p[e] * inv;
    gateo[t] = bp * inv;
    int pos = atomicAdd(&cnt[be], 1);
    list[be * T_TOK + pos] = t;
  }
}

// deterministic aux-loss reduction, one block
__global__ __launch_bounds__(256) void aux_kernel(
    const float* __restrict__ probs, const int* __restrict__ cnt,
    float* __restrict__ aux_out)
{
  __shared__ float sm[256 * 8];
  int tid = threadIdx.x;
  float s[8] = {0,0,0,0,0,0,0,0};
  for (int i = 0; i < 16; i++){
    int t = i * 256 + tid;
    #pragma unroll
    for (int e = 0; e < 8; e++) s[e] += probs[(size_t)t * 8 + e];
  }
  #pragma unroll
  for (int e = 0; e < 8; e++) sm[tid * 8 + e] = s[e];
  __syncthreads();
  for (int st = 128; st; st >>= 1){
    if (tid < st){
      #pragma unroll
      for (int e = 0; e < 8; e++) sm[tid * 8 + e] += sm[(tid + st) * 8 + e];
    }
    __syncthreads();
  }
  if (tid == 0){
    float a = 0.f;
    #pragma unroll
    for (int e = 0; e < 8; e++){
      float f = (float)cnt[e] / (float)T_TOK;
      float P = sm[e] / (float)T_TOK;
      a += f * P;
    }
    aux_out[0] = 0.01f * (float)NEXP * a;
  }
}

// GEMM1 (128x128, BK=64, 4 waves 2x2, single 32KB LDS, glds-A bf16 +
// reg-staged fp32 w1, 2 barriers/K-step, lb(256,3)) FUSED with cvt-w2 tail
// blocks [NG1, NG1+512): GEMM1 is glds-supply-bound at ~17% HBM, so the cvt's
// 201MB buffer traffic hides in its shadow / round-2 idle CUs (R19-measured).
__global__ __launch_bounds__(256, 3) void ffn_gemm1(
    const u16*  __restrict__ Aall,   // xb bf16 [4096][1024]
    const float* __restrict__ Bf,    // w1 fp32 [E][4096][1024]
    const float* __restrict__ bias,  // b1
    const int*  __restrict__ cnt,
    const int*  __restrict__ list,
    u16*  __restrict__ hOut,
    const float* __restrict__ w2,    // cvt src
    u16*  __restrict__ w2b)          // cvt dst
{
  int bid = blockIdx.x;
  int tid = threadIdx.x;

  if (bid >= NG1){
    const size_t TOT = (size_t)NEXP * DM * HID / 8;
    size_t stride = (size_t)512 * 256;
    for (size_t g = (size_t)(bid - NG1) * 256 + tid; g < TOT; g += stride){
      const float4* s = (const float4*)w2 + g * 2;
      float4 a = s[0], c = s[1];
      uint4 p;
      p.x = (unsigned)f2bf(a.x) | ((unsigned)f2bf(a.y) << 16);
      p.y = (unsigned)f2bf(a.z) | ((unsigned)f2bf(a.w) << 16);
      p.z = (unsigned)f2bf(c.x) | ((unsigned)f2bf(c.y) << 16);
      p.w = (unsigned)f2bf(c.z) | ((unsigned)f2bf(c.w) << 16);
      ((uint4*)w2b)[g] = p;
    }
    return;
  }

  constexpr int NT = 32, KS = 16;
  int nt = bid % NT;
  int t  = bid / NT;

  int e = -1, mt = 0, accT = 0;
  #pragma unroll
  for (int i = 0; i < NEXP; i++){
    int nti = (cnt[i] + 127) >> 7;
    if (e < 0 && t < accT + nti){ e = i; mt = t - accT; }
    accT += nti;
  }
  if (e < 0) return;
  int ne = cnt[e];
  int m0 = mt * 128;
  const int* lst = list + e * T_TOK;
  int n0 = nt * 128;

  __shared__ u16 As[8192];           // [128][64] swizzled, 16KB
  __shared__ u16 Bs[8192];

  int lane = tid & 63;
  int w    = tid >> 6;               // 4 waves
  int wm = w >> 1, wn = w & 1;       // 2M x 2N; wave out 64x64
  int fr = lane & 15, fq = lane >> 4;

  // A staging via glds (both-sides swizzle)
  const u16* aS[4]; int aDst[4];
  #pragma unroll
  for (int i = 0; i < 4; i++){
    int seg = w * 4 + i;
    int rr  = seg * 8 + (lane >> 3);
    int gg  = (lane & 7) ^ (rr & 7);
    int mrow = m0 + rr; if (mrow > ne - 1) mrow = ne - 1;
    aS[i] = Aall + (size_t)lst[mrow] * DM + gg * 8;
    aDst[i] = seg * 512;
  }

  // B reg-staging: 1024 chunks; thread owns 4
  const float* bS[4]; int bDst[4];
  #pragma unroll
  for (int i = 0; i < 4; i++){
    int cc = i * 256 + tid;
    int rr = cc >> 3, sl = cc & 7;
    int gg = sl ^ (rr & 7);
    bS[i] = Bf + ((size_t)e * HID + n0 + rr) * DM + gg * 8;
    bDst[i] = rr * 64 + sl * 8;
  }

  f32x4 acc[4][4];
  #pragma unroll
  for (int m = 0; m < 4; m++)
    #pragma unroll
    for (int n = 0; n < 4; n++)
      acc[m][n] = (f32x4){0.f, 0.f, 0.f, 0.f};

  float4 br0[4], br1[4];
  #pragma unroll
  for (int i = 0; i < 4; i++){
    const float4* s = (const float4*)bS[i];
    br0[i] = s[0]; br1[i] = s[1];
  }

  for (int ks = 0; ks < KS; ++ks){
    if (ks) __syncthreads();
    size_t ko = (size_t)ks * 64;
    #pragma unroll
    for (int i = 0; i < 4; i++) glds16(aS[i] + ko, &As[aDst[i]]);
    #pragma unroll
    for (int i = 0; i < 4; i++){
      uint4 pk;
      pk.x = (unsigned)f2bf(br0[i].x) | ((unsigned)f2bf(br0[i].y) << 16);
      pk.y = (unsigned)f2bf(br0[i].z) | ((unsigned)f2bf(br0[i].w) << 16);
      pk.z = (unsigned)f2bf(br1[i].x) | ((unsigned)f2bf(br1[i].y) << 16);
      pk.w = (unsigned)f2bf(br1[i].z) | ((unsigned)f2bf(br1[i].w) << 16);
      *(uint4*)&Bs[bDst[i]] = pk;
    }
    if (ks + 1 < KS){
      #pragma unroll
      for (int i = 0; i < 4; i++){
        const float4* s = (const float4*)(bS[i] + (ks + 1) * 64);
        br0[i] = s[0]; br1[i] = s[1];
      }
    }
    __syncthreads();
    #pragma unroll
    for (int kc = 0; kc < 2; kc++){
      short8 afr[4], bfr[4];
      #pragma unroll
      for (int m = 0; m < 4; m++){
        int row  = wm * 64 + m * 16 + fr;
        int slot = (kc * 4 + fq) ^ (row & 7);
        afr[m] = *(const short8*)&As[row * 64 + slot * 8];
      }
      #pragma unroll
      for (int n = 0; n < 4; n++){
        int row  = wn * 64 + n * 16 + fr;
        int slot = (kc * 4 + fq) ^ (row & 7);
        bfr[n] = *(const short8*)&Bs[row * 64 + slot * 8];
      }
      #pragma unroll
      for (int m = 0; m < 4; m++)
        #pragma unroll
        for (int n = 0; n < 4; n++)
          acc[m][n] = __builtin_amdgcn_mfma_f32_16x16x32_bf16(afr[m], bfr[n], acc[m][n], 0, 0, 0);
    }
  }

  // epilogue: gelu(acc+b1) -> h bf16
  #pragma unroll
  for (int n = 0; n < 4; n++){
    int col = n0 + wn * 64 + n * 16 + fr;
    float bv = bias[(size_t)e * HID + col];
    #pragma unroll
    for (int m = 0; m < 4; m++){
      int rbase = m0 + wm * 64 + m * 16 + fq * 4;
      f32x4 v = acc[m][n];
      #pragma unroll
      for (int i = 0; i < 4; i++){
        int mrow = rbase + i;
        if (mrow < ne){
          int tok = lst[mrow];
          float val = v[i] + bv;
          float gl = 0.5f * val * (1.0f + erff(val * 0.70710678118654752f));
          hOut[(size_t)tok * HID + col] = f2bf(gl);
        }
      }
    }
  }
}

// GEMM2, bf16 path (measured 93us floor): 128x128, BK=64, 4 waves, single
// 32KB LDS, glds-direct bf16 staging both operands, lb(256,3), split-K=4 ->
// PART (plain stores; R23 showed atomic epilogue costs +70us).
__global__ __launch_bounds__(256, 3) void ffn_gemm2(
    const u16*  __restrict__ Aall,   // h bf16 [4096][4096]
    const u16*  __restrict__ Bb,     // w2b bf16 [E][1024][4096]
    const float* __restrict__ bias,  // b2
    const int*  __restrict__ cnt,
    const int*  __restrict__ list,
    float* __restrict__ pOut)        // PART [4][4096][1024]
{
  constexpr int NT = 8, KS = 16;
  int bid = blockIdx.x;
  int nt = bid % NT;
  int r1 = bid / NT;
  int t  = r1 % MAXT;
  int sk = r1 / MAXT;

  int e = -1, mt = 0, accT = 0;
  #pragma unroll
  for (int i = 0; i < NEXP; i++){
    int nti = (cnt[i] + 127) >> 7;
    if (e < 0 && t < accT + nti){ e = i; mt = t - accT; }
    accT += nti;
  }
  if (e < 0) return;
  int ne = cnt[e];
  int m0 = mt * 128;
  const int* lst = list + e * T_TOK;
  int n0 = nt * 128;
  int koff = sk * (KS * 64);

  __shared__ u16 As[8192];
  __shared__ u16 Bs[8192];

  int tid  = threadIdx.x;
  int lane = tid & 63;
  int w    = tid >> 6;
  int wm = w >> 1, wn = w & 1;
  int fr = lane & 15, fq = lane >> 4;

  const u16* aS[4]; const u16* bS[4]; int dst[4];
  #pragma unroll
  for (int i = 0; i < 4; i++){
    int seg = w * 4 + i;
    int r   = seg * 8 + (lane >> 3);
    int g   = (lane & 7) ^ (r & 7);
    int mrow = m0 + r; if (mrow > ne - 1) mrow = ne - 1;
    aS[i] = Aall + (size_t)lst[mrow] * HID + koff + g * 8;
    bS[i] = Bb + (size_t)e * DM * HID + (size_t)(n0 + r) * HID + koff + g * 8;
    dst[i] = seg * 512;
  }

  f32x4 acc[4][4];
  #pragma unroll
  for (int m = 0; m < 4; m++)
    #pragma unroll
    for (int n = 0; n < 4; n++)
      acc[m][n] = (f32x4){0.f, 0.f, 0.f, 0.f};

  for (int ks = 0; ks < KS; ++ks){
    if (ks) __syncthreads();
    size_t ko = (size_t)ks * 64;
    #pragma unroll
    for (int i = 0; i < 4; i++) glds16(aS[i] + ko, &As[dst[i]]);
    #pragma unroll
    for (int i = 0; i < 4; i++) glds16(bS[i] + ko, &Bs[dst[i]]);
    __syncthreads();
    #pragma unroll
    for (int kc = 0; kc < 2; kc++){
      short8 afr[4], bfr[4];
      #pragma unroll
      for (int m = 0; m < 4; m++){
        int row  = wm * 64 + m * 16 + fr;
        int slot = (kc * 4 + fq) ^ (row & 7);
        afr[m] = *(const short8*)&As[row * 64 + slot * 8];
      }
      #pragma unroll
      for (int n = 0; n < 4; n++){
        int row  = wn * 64 + n * 16 + fr;
        int slot = (kc * 4 + fq) ^ (row & 7);
        bfr[n] = *(const short8*)&Bs[row * 64 + slot * 8];
      }
      #pragma unroll
      for (int m = 0; m < 4; m++)
        #pragma unroll
        for (int n = 0; n < 4; n++)
          acc[m][n] = __builtin_amdgcn_mfma_f32_16x16x32_bf16(afr[m], bfr[n], acc[m][n], 0, 0, 0);
    }
  }

  #pragma unroll
  for (int n = 0; n < 4; n++){
    int col = n0 + wn * 64 + n * 16 + fr;
    float bv = (sk == 0) ? bias[(size_t)e * DM + col] : 0.f;
    #pragma unroll
    for (int m = 0; m < 4; m++){
      int rbase = m0 + wm * 64 + m * 16 + fq * 4;
      f32x4 v = acc[m][n];
      #pragma unroll
      for (int i = 0; i < 4; i++){
        int mrow = rbase + i;
        if (mrow < ne){
          int tok = lst[mrow];
          pOut[((size_t)sk * T_TOK + tok) * DM + col] = v[i] + bv;
        }
      }
    }
  }
}

// out = gate * (part0+part1+part2+part3)   (b2 already in part0)
__global__ __launch_bounds__(256) void reduce_kernel(
    const float* __restrict__ part, const float* __restrict__ gate,
    float* __restrict__ out)
{
  size_t i = (size_t)blockIdx.x * 256 + threadIdx.x;
  constexpr size_t S = (size_t)T_TOK * DM / 4;
  const float4* p = (const float4*)part;
  float4 a = p[i], b = p[i + S], c = p[i + 2 * S], d = p[i + 3 * S];
  float g = gate[i >> 8];
  float4 o;
  o.x = (a.x + b.x + c.x + d.x) * g;
  o.y = (a.y + b.y + c.y + d.y) * g;
  o.z = (a.z + b.z + c.z + d.z) * g;
  o.w = (a.w + b.w + c.w + d.w) * g;
  ((float4*)out)[i] = o;
}

extern "C" void kernel_launch(void* const* d_in, const int* in_sizes, int n_in,
                              void* d_out, int out_size, void* d_ws, size_t ws_size,
                              hipStream_t stream) {
  const float* x   = (const float*)d_in[0];
  const float* gw  = (const float*)d_in[1];
  const float* w1  = (const float*)d_in[2];
  const float* b1  = (const float*)d_in[3];
  const float* w2  = (const float*)d_in[4];
  const float* b2  = (const float*)d_in[5];

  char* ws = (char*)d_ws;
  float* gateo = (float*)(ws + GATE_OFF);
  int*   cnt   = (int*)  (ws + CNT_OFF);
  int*   list  = (int*)  (ws + LIST_OFF);
  float* probs = (float*)(ws + PROBS_OFF);
  u16*   xb    = (u16*)  (ws + XB_OFF);
  u16*   h     = (u16*)  (ws + H_OFF);
  float* part  = (float*)(ws + PART_OFF);
  u16*   w2b   = (u16*)  (ws + W2B_OFF);

  float* out = (float*)d_out;
  float* aux = out + (size_t)T_TOK * DM;

  hipLaunchKernelGGL(zero_cnt_kernel, dim3(1), dim3(64), 0, stream, cnt);
  hipLaunchKernelGGL(gate_kernel, dim3(T_TOK / 4), dim3(256), 0, stream,
                     x, gw, gateo, cnt, list, probs, xb);
  hipLaunchKernelGGL(aux_kernel, dim3(1), dim3(256), 0, stream, probs, cnt, aux);

  // GEMM1 (fp32-direct w1) fused with cvt-w2 tail blocks
  hipLaunchKernelGGL(ffn_gemm1, dim3(NG1 + 512), dim3(256), 0, stream,
                     xb, w1, b1, cnt, list, h, w2, w2b);
  // GEMM2 (bf16 w2b), split-K=4 -> PART
  hipLaunchKernelGGL(ffn_gemm2, dim3(4 * MAXT * 8), dim3(256), 0, stream,
                     h, w2b, b2, cnt, list, part);
  hipLaunchKernelGGL(reduce_kernel, dim3(T_TOK * DM / 4 / 256), dim3(256), 0, stream,
                     part, gateo, out);
}